// Round 13
// baseline (382.391 us; speedup 1.0000x reference)
//
#include <hip/hip_runtime.h>
#include <math.h>

// Problem constants (from reference)
#define B_ 16
#define P_ 131072
#define G_ 32
constexpr float OVER_THR = 0.35f;
constexpr float VAR0 = 0.1f;
constexpr float VAR1 = 0.2f;
constexpr int NEG_POS = 7;
constexpr int UNR = 8;                         // priors per thread in k_match
constexpr int LOSS_X = P_ / 256;               // 512 blocks per image in k_loss
constexpr int LOSS_BLOCKS = LOSS_X * B_;       // 8192 partials
constexpr int NBIN13 = 8192;                   // level 1: float bits 31..19
constexpr int NBIN8 = 256;                     // level 2: bits 18..11
constexpr int NBIN11 = 2048;                   // level 3: bits 10..0
constexpr int SCAN_BLKS = 16;                  // blocks per image in scans

// ---------------- helpers ----------------
__device__ inline float s1(float d) {            // smooth L1
    d = fabsf(d);
    return d < 1.f ? 0.5f * d * d : d - 0.5f;
}

__device__ inline unsigned long long shfl_xor_u64(unsigned long long x, int m) {
    unsigned lo = (unsigned)x, hi = (unsigned)(x >> 32);
    lo = __shfl_xor(lo, m);
    hi = __shfl_xor(hi, m);
    return ((unsigned long long)hi << 32) | lo;
}

// Block-parallel (1024 thr) top-k bin select over NB global bins (descending).
// Verified correct in rounds 9/10. Writes *sbin / *srem from the unique
// crossing thread; trailing barrier makes them visible to all threads.
template <int NB>
__device__ void blk_select(const unsigned* __restrict__ gc, unsigned rem,
                           int* sbin, unsigned* srem) {
    constexpr int CHUNK = (NB + 1023) / 1024;
    const int tid = threadIdx.x;
    unsigned cnt[CHUNK];
    unsigned csum = 0;
#pragma unroll
    for (int j = 0; j < CHUNK; ++j) {
        int idx = tid * CHUNK + j;
        unsigned c = (idx < NB) ? gc[idx] : 0u;
        cnt[j] = c; csum += c;
    }
    __shared__ unsigned ss[1024];
    ss[tid] = csum;
    __syncthreads();
    for (int off = 1; off < 1024; off <<= 1) {       // suffix scan (desc bins)
        unsigned o = (tid + off < 1024) ? ss[tid + off] : 0u;
        __syncthreads();
        ss[tid] += o;
        __syncthreads();
    }
    unsigned incl = ss[tid], excl = incl - csum;
    if (excl < rem && incl >= rem) {
        unsigned r = rem - excl, cum = 0;
        int sb_ = tid * CHUNK;
#pragma unroll
        for (int j = CHUNK - 1; j >= 0; --j) {
            unsigned c = cnt[j];
            if (cum + c >= r) { sb_ = tid * CHUNK + j; r -= cum; break; }
            cum += c;
        }
        *sbin = sb_; *srem = r;
    }
    __syncthreads();
}

// ---------------- kernels ----------------
// k_match converged at ~60us across 6 variants (rounds 5-12); round-12 form
// kept: s_load truth boxes, u8 bt output, u64 butterfly per g.
__global__ __launch_bounds__(256, 3) void k_match(
        const float4* __restrict__ priors4, const float* __restrict__ targets,
        unsigned char* __restrict__ bt, unsigned long long* __restrict__ pack) {
    const int b = blockIdx.y;
    const int base = blockIdx.x * (256 * UNR);
    const int tid = threadIdx.x;
    __shared__ unsigned long long red[G_][4];

    float px1[UNR], py1[UNR], px2[UNR], py2[UNR], pap[UNR], best[UNR];
    int bidx[UNR];
#pragma unroll
    for (int j = 0; j < UNR; ++j) {
        float4 pr = priors4[base + j * 256 + tid];
        px1[j] = pr.x - pr.z * 0.5f;  py1[j] = pr.y - pr.w * 0.5f;
        px2[j] = pr.x + pr.z * 0.5f;  py2[j] = pr.y + pr.w * 0.5f;
        pap[j] = pr.z * pr.w;
        best[j] = -1.0f; bidx[j] = 0;
    }
    const int lane = tid & 63, wave = tid >> 6;
    const float* tgb = targets + (size_t)b * G_ * 15;
#pragma unroll 1
    for (int g = 0; g < G_; ++g) {
        const float* tp = tgb + g * 15;        // block-uniform -> s_load
        float t0 = tp[0], t1 = tp[1], t2 = tp[2], t3 = tp[3];
        float ta = (t2 - t0) * (t3 - t1);
        float gb = -1.0f; int gj = 0;
#pragma unroll
        for (int j = 0; j < UNR; ++j) {
            float iw = fminf(t2, px2[j]) - fmaxf(t0, px1[j]);
            float ih = fminf(t3, py2[j]) - fmaxf(t1, py1[j]);
            float inter = fmaxf(iw, 0.f) * fmaxf(ih, 0.f);
            float iou = inter * __builtin_amdgcn_rcpf(ta + pap[j] - inter);
            if (iou > best[j]) { best[j] = iou; bidx[j] = g; }  // first-wins ties
            if (iou > gb) { gb = iou; gj = j; }   // first-j wins = lowest p
        }
        unsigned p = (unsigned)(base + (gj << 8) + tid);
        unsigned long long pk =
            ((unsigned long long)__float_as_uint(gb) << 32) | (unsigned)(~p);
#pragma unroll
        for (int off = 32; off > 0; off >>= 1) {
            unsigned long long o = shfl_xor_u64(pk, off);
            if (o > pk) pk = o;
        }
        if (lane == 0) red[g][wave] = pk;
    }
    __syncthreads();
    if (tid < G_) {
        unsigned long long m = red[tid][0];
#pragma unroll
        for (int w = 1; w < 4; ++w) if (red[tid][w] > m) m = red[tid][w];
        atomicMax(&pack[b * G_ + tid], m);
    }
#pragma unroll
    for (int j = 0; j < UNR; ++j) {
        int p = base + j * 256 + tid;
        bt[(size_t)b * P_ + p] =
            (unsigned char)(bidx[j] | (best[j] >= OVER_THR ? 64 : 0));
    }
}

// Sequential per image: scatter with last-g-wins (numpy semantics).
__global__ void k_override(const unsigned long long* __restrict__ pack,
                           unsigned char* __restrict__ bt) {
    int b = threadIdx.x;
    if (b >= B_) return;
    for (int g = 0; g < G_; ++g) {
        unsigned long long pk = pack[b * G_ + g];
        unsigned p = ~(unsigned)(pk & 0xFFFFFFFFull);
        if (p < P_) bt[(size_t)b * P_ + p] = (unsigned char)(g | 64);
    }
}

// Per prior: CE; positives: smooth-L1 on encoded loc/landm. Partials per block.
__global__ __launch_bounds__(256) void k_loss(
        const float2* __restrict__ conf2, const float4* __restrict__ loc4,
        const float* __restrict__ landm, const float4* __restrict__ priors4,
        const float* __restrict__ targets,
        const unsigned char* __restrict__ bt,
        float* __restrict__ ce_neg,
        double* __restrict__ pb, double* __restrict__ pl,
        double* __restrict__ pc, int* __restrict__ pn) {
    const int b = blockIdx.y;
    const int p = blockIdx.x * 256 + threadIdx.x;
    const int tid = threadIdx.x;
    __shared__ float tg[G_ * 15];
    for (int i = tid; i < G_ * 15; i += 256) tg[i] = targets[(size_t)b * G_ * 15 + i];
    __syncthreads();

    const size_t gp = (size_t)b * P_ + p;
    unsigned char bv = bt[gp];
    int ti = bv & 63;
    bool thr_ok = (bv & 64) != 0;               // ov >= OVER_THR (or override)
    const float* t = &tg[ti * 15];
    float label = t[14];
    int conf_t = thr_ok ? (int)label : 0;
    bool pos = conf_t > 0;
    int cls = conf_t > 0 ? conf_t : 0;

    float2 c2 = conf2[gp];
    float mx = fmaxf(c2.x, c2.y);
    float lse = mx + logf(expf(c2.x - mx) + expf(c2.y - mx));
    float ce = lse - (cls ? c2.y : c2.x);
    ce_neg[gp] = (!pos && conf_t >= 0) ? ce : 0.f;

    float lb = 0.f, ll = 0.f;
    if (pos) {
        float4 pr = priors4[p];
        float vx = VAR0 * pr.z, vy = VAR0 * pr.w;
        float g0 = ((t[0] + t[2]) * 0.5f - pr.x) / vx;
        float g1 = ((t[1] + t[3]) * 0.5f - pr.y) / vy;
        float g2 = logf((t[2] - t[0]) / pr.z) / VAR1;
        float g3 = logf((t[3] - t[1]) / pr.w) / VAR1;
        float4 ld = loc4[gp];
        lb = s1(ld.x - g0) + s1(ld.y - g1) + s1(ld.z - g2) + s1(ld.w - g3);
        const float* lmp = landm + gp * 10;
#pragma unroll
        for (int i = 0; i < 5; ++i) {
            float2 lm = *(const float2*)(lmp + 2 * i);
            ll += s1(lm.x - (t[4 + 2 * i] - pr.x) / vx)
                + s1(lm.y - (t[5 + 2 * i] - pr.y) / vy);
        }
    }
    double vb = lb, vl = ll, vc = pos ? (double)ce : 0.0;
    int vp = pos ? 1 : 0;
#pragma unroll
    for (int off = 32; off > 0; off >>= 1) {
        vb += __shfl_xor(vb, off);
        vl += __shfl_xor(vl, off);
        vc += __shfl_xor(vc, off);
        vp += __shfl_xor(vp, off);
    }
    __shared__ double rb[4], rl[4], rc[4];
    __shared__ int rp[4];
    int lane = tid & 63, wave = tid >> 6;
    if (lane == 0) { rb[wave] = vb; rl[wave] = vl; rc[wave] = vc; rp[wave] = vp; }
    __syncthreads();
    if (tid == 0) {
        double sb = 0, sl = 0, sc = 0; int sp = 0;
        for (int w = 0; w < 4; ++w) { sb += rb[w]; sl += rl[w]; sc += rc[w]; sp += rp[w]; }
        int bi = blockIdx.y * LOSS_X + blockIdx.x;
        pb[bi] = sb; pl[bi] = sl; pc[bi] = sc; pn[bi] = sp;
    }
}

// Scan 1 + ticket tail: 13-bit count histogram; last block of the image sums
// num_pos from k_loss partials and runs the 13-bit select (replaces k_sel13).
// Hists are count-only u32 (round-6's regression was LDS FLOAT atomicAdd =
// CAS loop; avoided).
__global__ __launch_bounds__(1024) void k_hist13(
        const float* __restrict__ ce_neg, unsigned* __restrict__ hist,
        const int* __restrict__ pn, int* __restrict__ tick,
        int* __restrict__ sel, int* __restrict__ remk, int* __restrict__ npos) {
    const int b = blockIdx.y;
    const int tid = threadIdx.x;
    __shared__ unsigned h[NBIN13];
    for (int i = tid; i < NBIN13; i += 1024) h[i] = 0;
    __syncthreads();
    const float4* v4 = (const float4*)(ce_neg + (size_t)b * P_);
    const int c4 = P_ / SCAN_BLKS / 4;
    const int s4 = blockIdx.x * c4;
    for (int i = s4 + tid; i < s4 + c4; i += 1024) {
        float4 x = v4[i];
        atomicAdd(&h[__float_as_uint(x.x) >> 19], 1u);
        atomicAdd(&h[__float_as_uint(x.y) >> 19], 1u);
        atomicAdd(&h[__float_as_uint(x.z) >> 19], 1u);
        atomicAdd(&h[__float_as_uint(x.w) >> 19], 1u);
    }
    __syncthreads();
    unsigned* gh = hist + b * NBIN13;
    for (int i = tid; i < NBIN13; i += 1024)
        if (h[i]) atomicAdd(&gh[i], h[i]);
    __threadfence();
    __shared__ int amLast;
    if (tid == 0) amLast = (atomicAdd(&tick[b], 1) == SCAN_BLKS - 1);
    __syncthreads();
    if (!amLast) return;
    __threadfence();
    // ---- tail: npos + 13-bit select ----
    int v = (tid < LOSS_X) ? pn[b * LOSS_X + tid] : 0;
#pragma unroll
    for (int off = 32; off > 0; off >>= 1) v += __shfl_xor(v, off);
    __shared__ int rnp[16];
    __shared__ long long s_k;
    int lane = tid & 63, wave = tid >> 6;
    if (lane == 0) rnp[wave] = v;
    __syncthreads();
    if (tid == 0) {
        int s = 0;
        for (int w = 0; w < 16; ++w) s += rnp[w];
        npos[b] = s;
        long long k = (long long)NEG_POS * s;
        if (k > P_ - 1) k = P_ - 1;
        s_k = k;
    }
    __syncthreads();
    long long k = s_k;
    if (k <= 0) { if (tid == 0) sel[b] = -1; return; }
    __shared__ int sb_;
    __shared__ unsigned sr_;
    blk_select<NBIN13>(gh, (unsigned)k, &sb_, &sr_);
    if (tid == 0) { sel[b] = sb_; remk[b] = (int)sr_; }
}

// Scan 2 + ticket tail: 8-bit histogram of in-bin elements; last block runs
// the 8-bit select and extends the prefix (replaces k_sel8).
__global__ __launch_bounds__(1024) void k_hist8(
        const float* __restrict__ ce_neg, const int* __restrict__ sel,
        unsigned* __restrict__ hist8, int* __restrict__ tick,
        unsigned* __restrict__ pref, int* __restrict__ remk) {
    const int b = blockIdx.y;
    const int tid = threadIdx.x;
    const int s13 = sel[b];
    if (s13 >= 0) {
        __shared__ unsigned h[NBIN8];
        if (tid < NBIN8) h[tid] = 0;
        __syncthreads();
        const float4* v4 = (const float4*)(ce_neg + (size_t)b * P_);
        const int c4 = P_ / SCAN_BLKS / 4;
        const int s4 = blockIdx.x * c4;
        for (int i = s4 + tid; i < s4 + c4; i += 1024) {
            float4 x = v4[i];
            unsigned u0 = __float_as_uint(x.x), u1 = __float_as_uint(x.y);
            unsigned u2 = __float_as_uint(x.z), u3 = __float_as_uint(x.w);
            if ((int)(u0 >> 19) == s13) atomicAdd(&h[(u0 >> 11) & 255u], 1u);
            if ((int)(u1 >> 19) == s13) atomicAdd(&h[(u1 >> 11) & 255u], 1u);
            if ((int)(u2 >> 19) == s13) atomicAdd(&h[(u2 >> 11) & 255u], 1u);
            if ((int)(u3 >> 19) == s13) atomicAdd(&h[(u3 >> 11) & 255u], 1u);
        }
        __syncthreads();
        if (tid < NBIN8 && h[tid]) atomicAdd(&hist8[b * NBIN8 + tid], h[tid]);
    }
    __threadfence();
    __shared__ int amLast;
    if (tid == 0) amLast = (atomicAdd(&tick[b], 1) == SCAN_BLKS - 1);
    __syncthreads();
    if (!amLast || s13 < 0) return;
    __threadfence();
    __shared__ int sb_;
    __shared__ unsigned sr_;
    blk_select<NBIN8>(hist8 + b * NBIN8, (unsigned)remk[b], &sb_, &sr_);
    if (tid == 0) {
        pref[b] = ((unsigned)s13 << 8) | (unsigned)sb_;   // 21-bit prefix
        remk[b] = (int)sr_;
    }
}

// Scan 3 + ticket tail: 11-bit histogram of in-prefix elements; last block
// runs the final select -> exact threshold T, writes thr[b] (sentinel if no
// negatives) and adds the tie term rem*T (replaces k_sel11).
__global__ __launch_bounds__(1024) void k_hist11(
        const float* __restrict__ ce_neg, const int* __restrict__ sel,
        const unsigned* __restrict__ pref, unsigned* __restrict__ hist11,
        int* __restrict__ tick, const int* __restrict__ remk,
        unsigned* __restrict__ thr, double* __restrict__ tot) {
    const int b = blockIdx.y;
    const int tid = threadIdx.x;
    const int s13 = sel[b];
    if (s13 >= 0) {
        const unsigned pf = pref[b];
        __shared__ unsigned h[NBIN11];
        for (int i = tid; i < NBIN11; i += 1024) h[i] = 0;
        __syncthreads();
        const float4* v4 = (const float4*)(ce_neg + (size_t)b * P_);
        const int c4 = P_ / SCAN_BLKS / 4;
        const int s4 = blockIdx.x * c4;
        for (int i = s4 + tid; i < s4 + c4; i += 1024) {
            float4 x = v4[i];
            unsigned u0 = __float_as_uint(x.x), u1 = __float_as_uint(x.y);
            unsigned u2 = __float_as_uint(x.z), u3 = __float_as_uint(x.w);
            if ((u0 >> 11) == pf) atomicAdd(&h[u0 & 2047u], 1u);
            if ((u1 >> 11) == pf) atomicAdd(&h[u1 & 2047u], 1u);
            if ((u2 >> 11) == pf) atomicAdd(&h[u2 & 2047u], 1u);
            if ((u3 >> 11) == pf) atomicAdd(&h[u3 & 2047u], 1u);
        }
        __syncthreads();
        unsigned* gh = hist11 + b * NBIN11;
        for (int i = tid; i < NBIN11; i += 1024)
            if (h[i]) atomicAdd(&gh[i], h[i]);
    }
    __threadfence();
    __shared__ int amLast;
    if (tid == 0) amLast = (atomicAdd(&tick[b], 1) == SCAN_BLKS - 1);
    __syncthreads();
    if (!amLast) return;
    __threadfence();
    if (s13 < 0) { if (tid == 0) thr[b] = 0xFFFFFFFFu; return; }
    __shared__ int sb_;
    __shared__ unsigned sr_;
    blk_select<NBIN11>(hist11 + b * NBIN11, (unsigned)remk[b], &sb_, &sr_);
    if (tid == 0) {
        unsigned t = (pref[b] << 11) | (unsigned)sb_;
        thr[b] = t;
        atomicAdd(&tot[2], (double)sr_ * (double)__uint_as_float(t));  // ties
    }
}

// Scan 4 + global ticket tail: sum of elements strictly above threshold;
// last block of ALL 256 reduces the k_loss partials and writes the 3 outputs
// (replaces k_final).
__global__ __launch_bounds__(1024) void k_sumtop(
        const float* __restrict__ ce_neg, const unsigned* __restrict__ thr,
        double* __restrict__ tot, int* __restrict__ tickS,
        const double* __restrict__ pb, const double* __restrict__ pl,
        const double* __restrict__ pc, const int* __restrict__ npos,
        float* __restrict__ out) {
    const int b = blockIdx.y;
    const int tid = threadIdx.x;
    const unsigned t = thr[b];
    int lane = tid & 63, wave = tid >> 6;
    if (t != 0xFFFFFFFFu) {
        const float4* v4 = (const float4*)(ce_neg + (size_t)b * P_);
        const int c4 = P_ / SCAN_BLKS / 4;
        const int s4 = blockIdx.x * c4;
        double loc = 0;
        for (int i = s4 + tid; i < s4 + c4; i += 1024) {
            float4 x = v4[i];
            if (__float_as_uint(x.x) > t) loc += x.x;
            if (__float_as_uint(x.y) > t) loc += x.y;
            if (__float_as_uint(x.z) > t) loc += x.z;
            if (__float_as_uint(x.w) > t) loc += x.w;
        }
#pragma unroll
        for (int off = 32; off > 0; off >>= 1) loc += __shfl_xor(loc, off);
        __shared__ double rs[16];
        if (lane == 0) rs[wave] = loc;
        __syncthreads();
        if (tid == 0) {
            double s = 0;
            for (int w = 0; w < 16; ++w) s += rs[w];
            atomicAdd(&tot[2], s);
        }
    }
    __threadfence();
    __shared__ int amLast;
    if (tid == 0) amLast = (atomicAdd(tickS, 1) == SCAN_BLKS * B_ - 1);
    __syncthreads();
    if (!amLast) return;
    __threadfence();
    // ---- tail: reduce loss partials + write outputs ----
    double sb = 0, sl = 0, sc = 0;
    for (int i = tid; i < LOSS_BLOCKS; i += 1024) {
        sb += pb[i]; sl += pl[i]; sc += pc[i];
    }
#pragma unroll
    for (int off = 32; off > 0; off >>= 1) {
        sb += __shfl_xor(sb, off);
        sl += __shfl_xor(sl, off);
        sc += __shfl_xor(sc, off);
    }
    __shared__ double rb[16], rl[16], rc[16];
    if (lane == 0) { rb[wave] = sb; rl[wave] = sl; rc[wave] = sc; }
    __syncthreads();
    if (tid == 0) {
        double b2 = 0, l2 = 0, c2 = 0;
        for (int w = 0; w < 16; ++w) { b2 += rb[w]; l2 += rl[w]; c2 += rc[w]; }
        long long tp = 0;
        for (int i = 0; i < B_; ++i) tp += npos[i];
        double n = tp > 0 ? (double)tp : 1.0;
        out[0] = (float)(b2 / n);             // loss_box
        out[1] = (float)((c2 + tot[2]) / n);  // loss_c (pos part + mined negs)
        out[2] = (float)(l2 / n);             // loss_landm
    }
}

// ---------------- launch ----------------
extern "C" void kernel_launch(void* const* d_in, const int* in_sizes, int n_in,
                              void* d_out, int out_size, void* d_ws, size_t ws_size,
                              hipStream_t stream) {
    const float* conf    = (const float*)d_in[0];
    const float* loc     = (const float*)d_in[1];
    const float* landm   = (const float*)d_in[2];
    const float* priors  = (const float*)d_in[3];
    const float* targets = (const float*)d_in[4];

    char* ws = (char*)d_ws;
    double* tot = (double*)ws;                                   // 4 doubles @0
    int* npos = (int*)(ws + 64);
    int* sel  = (int*)(ws + 128);
    int* remk = (int*)(ws + 192);
    unsigned* pref = (unsigned*)(ws + 256);
    unsigned* thr  = (unsigned*)(ws + 320);
    int* tick1 = (int*)(ws + 384);
    int* tick2 = (int*)(ws + 448);
    int* tick3 = (int*)(ws + 512);
    int* tickS = (int*)(ws + 576);
    unsigned long long* pack = (unsigned long long*)(ws + 1024); // 512 u64 = 4KB
    unsigned* hist13 = (unsigned*)(ws + 5120);                   // 512 KB
    unsigned* hist8  = hist13 + (size_t)B_ * NBIN13;             // 16 KB
    unsigned* hist11 = hist8 + (size_t)B_ * NBIN8;               // 128 KB
    size_t zero_bytes = 5120 + (size_t)B_ * (NBIN13 + NBIN8 + NBIN11) * 4;
    size_t big = (zero_bytes + 255) & ~(size_t)255;
    size_t BP = (size_t)B_ * P_;
    unsigned char* bt = (unsigned char*)(ws + big);              // 2 MB (u8)
    float* ce_neg = (float*)(ws + big + BP);                     // 8.4 MB
    char* part = ws + big + BP * 5;
    double* pb = (double*)part;
    double* pl = (double*)(part + LOSS_BLOCKS * 8);
    double* pc = (double*)(part + LOSS_BLOCKS * 16);
    int*    pn = (int*)(part + LOSS_BLOCKS * 24);

    // one memset zeroes: tot, npos, sel/remk/pref/thr, tickets, pack, hists
    hipMemsetAsync(ws, 0, zero_bytes, stream);
    k_match<<<dim3(P_ / (256 * UNR), B_), 256, 0, stream>>>(
        (const float4*)priors, targets, bt, pack);
    k_override<<<1, 64, 0, stream>>>(pack, bt);
    k_loss<<<dim3(LOSS_X, B_), 256, 0, stream>>>(
        (const float2*)conf, (const float4*)loc, landm, (const float4*)priors,
        targets, bt, ce_neg, pb, pl, pc, pn);
    k_hist13<<<dim3(SCAN_BLKS, B_), 1024, 0, stream>>>(
        ce_neg, hist13, pn, tick1, sel, remk, npos);
    k_hist8<<<dim3(SCAN_BLKS, B_), 1024, 0, stream>>>(
        ce_neg, sel, hist8, tick2, pref, remk);
    k_hist11<<<dim3(SCAN_BLKS, B_), 1024, 0, stream>>>(
        ce_neg, sel, pref, hist11, tick3, remk, thr, tot);
    k_sumtop<<<dim3(SCAN_BLKS, B_), 1024, 0, stream>>>(
        ce_neg, thr, tot, tickS, pb, pl, pc, npos, (float*)d_out);
}

// Round 14
// 126.803 us; speedup vs baseline: 3.0156x; 3.0156x over previous
//
#include <hip/hip_runtime.h>
#include <math.h>

// Problem constants (from reference)
#define B_ 16
#define P_ 131072
#define G_ 32
constexpr float OVER_THR = 0.35f;
constexpr float VAR0 = 0.1f;
constexpr float VAR1 = 0.2f;
constexpr int NEG_POS = 7;
constexpr int UNR = 8;                         // priors per thread in k_match
constexpr int LOSS_X = P_ / 256;               // 512 blocks per image in k_loss
constexpr int LOSS_BLOCKS = LOSS_X * B_;       // 8192 partials
constexpr int NBIN13 = 8192;                   // level 1: float bits 31..19
constexpr int NBIN8 = 256;                     // level 2: bits 18..11
constexpr int NBIN11 = 2048;                   // level 3: bits 10..0
constexpr int SCAN_BLKS = 16;                  // blocks per image in scans

// ---------------- helpers ----------------
__device__ inline float s1(float d) {            // smooth L1
    d = fabsf(d);
    return d < 1.f ? 0.5f * d * d : d - 0.5f;
}

__device__ inline unsigned long long shfl_xor_u64(unsigned long long x, int m) {
    unsigned lo = (unsigned)x, hi = (unsigned)(x >> 32);
    lo = __shfl_xor(lo, m);
    hi = __shfl_xor(hi, m);
    return ((unsigned long long)hi << 32) | lo;
}

// Block-parallel top-k bin selection (256 threads).
template <int NB>
__device__ void topk_select(const unsigned* __restrict__ h, unsigned rem,
                            int* out_bin, unsigned* out_rem) {
    constexpr int CHUNK = NB / 256;
    const int tid = threadIdx.x;
    unsigned cnt[CHUNK];
    unsigned csum = 0;
#pragma unroll
    for (int j = 0; j < CHUNK; ++j) { cnt[j] = h[tid * CHUNK + j]; csum += cnt[j]; }
    __shared__ unsigned ss[256];
    ss[tid] = csum;
    __syncthreads();
    // Hillis-Steele suffix scan: ss[t] = sum over threads >= t (higher bins)
    for (int off = 1; off < 256; off <<= 1) {
        unsigned other = (tid + off < 256) ? ss[tid + off] : 0u;
        __syncthreads();
        ss[tid] += other;
        __syncthreads();
    }
    unsigned incl = ss[tid];
    unsigned excl = incl - csum;               // strictly above this chunk
    if (excl < rem && incl >= rem) {           // crossing chunk (unique)
        unsigned r = rem - excl, cum = 0;
        int selbin = tid * CHUNK;
#pragma unroll
        for (int j = CHUNK - 1; j >= 0; --j) {
            unsigned c = cnt[j];
            if (cum + c >= r) { selbin = tid * CHUNK + j; r = r - cum; break; }
            cum += c;
        }
        *out_bin = selbin;
        *out_rem = r;
    }
}

// ---------------- kernels ----------------
// k_match converged at ~60us across 6 variants (rounds 5-12); round-12 form:
// s_load truth boxes, u8 bt output, u64 butterfly per g.
__global__ __launch_bounds__(256, 3) void k_match(
        const float4* __restrict__ priors4, const float* __restrict__ targets,
        unsigned char* __restrict__ bt, unsigned long long* __restrict__ pack) {
    const int b = blockIdx.y;
    const int base = blockIdx.x * (256 * UNR);
    const int tid = threadIdx.x;
    __shared__ unsigned long long red[G_][4];

    float px1[UNR], py1[UNR], px2[UNR], py2[UNR], pap[UNR], best[UNR];
    int bidx[UNR];
#pragma unroll
    for (int j = 0; j < UNR; ++j) {
        float4 pr = priors4[base + j * 256 + tid];
        px1[j] = pr.x - pr.z * 0.5f;  py1[j] = pr.y - pr.w * 0.5f;
        px2[j] = pr.x + pr.z * 0.5f;  py2[j] = pr.y + pr.w * 0.5f;
        pap[j] = pr.z * pr.w;
        best[j] = -1.0f; bidx[j] = 0;
    }
    const int lane = tid & 63, wave = tid >> 6;
    const float* tgb = targets + (size_t)b * G_ * 15;
#pragma unroll 1
    for (int g = 0; g < G_; ++g) {
        const float* tp = tgb + g * 15;        // block-uniform -> s_load
        float t0 = tp[0], t1 = tp[1], t2 = tp[2], t3 = tp[3];
        float ta = (t2 - t0) * (t3 - t1);
        float gb = -1.0f; int gj = 0;
#pragma unroll
        for (int j = 0; j < UNR; ++j) {
            float iw = fminf(t2, px2[j]) - fmaxf(t0, px1[j]);
            float ih = fminf(t3, py2[j]) - fmaxf(t1, py1[j]);
            float inter = fmaxf(iw, 0.f) * fmaxf(ih, 0.f);
            float iou = inter * __builtin_amdgcn_rcpf(ta + pap[j] - inter);
            if (iou > best[j]) { best[j] = iou; bidx[j] = g; }  // first-wins ties
            if (iou > gb) { gb = iou; gj = j; }   // first-j wins = lowest p
        }
        unsigned p = (unsigned)(base + (gj << 8) + tid);
        unsigned long long pk =
            ((unsigned long long)__float_as_uint(gb) << 32) | (unsigned)(~p);
#pragma unroll
        for (int off = 32; off > 0; off >>= 1) {
            unsigned long long o = shfl_xor_u64(pk, off);
            if (o > pk) pk = o;
        }
        if (lane == 0) red[g][wave] = pk;
    }
    __syncthreads();
    if (tid < G_) {
        unsigned long long m = red[tid][0];
#pragma unroll
        for (int w = 1; w < 4; ++w) if (red[tid][w] > m) m = red[tid][w];
        atomicMax(&pack[b * G_ + tid], m);
    }
#pragma unroll
    for (int j = 0; j < UNR; ++j) {
        int p = base + j * 256 + tid;
        bt[(size_t)b * P_ + p] =
            (unsigned char)(bidx[j] | (best[j] >= OVER_THR ? 64 : 0));
    }
}

// Sequential per image: scatter with last-g-wins (numpy semantics).
__global__ void k_override(const unsigned long long* __restrict__ pack,
                           unsigned char* __restrict__ bt) {
    int b = threadIdx.x;
    if (b >= B_) return;
    for (int g = 0; g < G_; ++g) {
        unsigned long long pk = pack[b * G_ + g];
        unsigned p = ~(unsigned)(pk & 0xFFFFFFFFull);
        if (p < P_) bt[(size_t)b * P_ + p] = (unsigned char)(g | 64);
    }
}

// Per prior: CE; positives: smooth-L1 on encoded loc/landm. Partials per block.
__global__ __launch_bounds__(256) void k_loss(
        const float2* __restrict__ conf2, const float4* __restrict__ loc4,
        const float* __restrict__ landm, const float4* __restrict__ priors4,
        const float* __restrict__ targets,
        const unsigned char* __restrict__ bt,
        float* __restrict__ ce_neg,
        double* __restrict__ pb, double* __restrict__ pl,
        double* __restrict__ pc, int* __restrict__ pn) {
    const int b = blockIdx.y;
    const int p = blockIdx.x * 256 + threadIdx.x;
    const int tid = threadIdx.x;
    __shared__ float tg[G_ * 15];
    for (int i = tid; i < G_ * 15; i += 256) tg[i] = targets[(size_t)b * G_ * 15 + i];
    __syncthreads();

    const size_t gp = (size_t)b * P_ + p;
    unsigned char bv = bt[gp];
    int ti = bv & 63;
    bool thr_ok = (bv & 64) != 0;               // ov >= OVER_THR (or override)
    const float* t = &tg[ti * 15];
    float label = t[14];
    int conf_t = thr_ok ? (int)label : 0;
    bool pos = conf_t > 0;
    int cls = conf_t > 0 ? conf_t : 0;

    float2 c2 = conf2[gp];
    float mx = fmaxf(c2.x, c2.y);
    float lse = mx + logf(expf(c2.x - mx) + expf(c2.y - mx));
    float ce = lse - (cls ? c2.y : c2.x);
    ce_neg[gp] = (!pos && conf_t >= 0) ? ce : 0.f;

    float lb = 0.f, ll = 0.f;
    if (pos) {
        float4 pr = priors4[p];
        float vx = VAR0 * pr.z, vy = VAR0 * pr.w;
        float g0 = ((t[0] + t[2]) * 0.5f - pr.x) / vx;
        float g1 = ((t[1] + t[3]) * 0.5f - pr.y) / vy;
        float g2 = logf((t[2] - t[0]) / pr.z) / VAR1;
        float g3 = logf((t[3] - t[1]) / pr.w) / VAR1;
        float4 ld = loc4[gp];
        lb = s1(ld.x - g0) + s1(ld.y - g1) + s1(ld.z - g2) + s1(ld.w - g3);
        const float* lmp = landm + gp * 10;
#pragma unroll
        for (int i = 0; i < 5; ++i) {
            float2 lm = *(const float2*)(lmp + 2 * i);
            ll += s1(lm.x - (t[4 + 2 * i] - pr.x) / vx)
                + s1(lm.y - (t[5 + 2 * i] - pr.y) / vy);
        }
    }
    double vb = lb, vl = ll, vc = pos ? (double)ce : 0.0;
    int vp = pos ? 1 : 0;
#pragma unroll
    for (int off = 32; off > 0; off >>= 1) {
        vb += __shfl_xor(vb, off);
        vl += __shfl_xor(vl, off);
        vc += __shfl_xor(vc, off);
        vp += __shfl_xor(vp, off);
    }
    __shared__ double rb[4], rl[4], rc[4];
    __shared__ int rp[4];
    int lane = tid & 63, wave = tid >> 6;
    if (lane == 0) { rb[wave] = vb; rl[wave] = vl; rc[wave] = vc; rp[wave] = vp; }
    __syncthreads();
    if (tid == 0) {
        double sb = 0, sl = 0, sc = 0; int sp = 0;
        for (int w = 0; w < 4; ++w) { sb += rb[w]; sl += rl[w]; sc += rc[w]; sp += rp[w]; }
        int bi = blockIdx.y * LOSS_X + blockIdx.x;
        pb[bi] = sb; pl[bi] = sl; pc[bi] = sc; pn[bi] = sp;
    }
}

// Scan 1: 13-bit count histogram of ce_neg float bits, per image. float4 loads.
__global__ __launch_bounds__(1024) void k_hist13(
        const float* __restrict__ ce_neg, unsigned* __restrict__ hist) {
    const int b = blockIdx.y;
    const int tid = threadIdx.x;
    __shared__ unsigned h[NBIN13];
    for (int i = tid; i < NBIN13; i += 1024) h[i] = 0;
    __syncthreads();
    const float4* v4 = (const float4*)(ce_neg + (size_t)b * P_);
    const int c4 = P_ / SCAN_BLKS / 4;
    const int s4 = blockIdx.x * c4;
    for (int i = s4 + tid; i < s4 + c4; i += 1024) {
        float4 x = v4[i];
        atomicAdd(&h[__float_as_uint(x.x) >> 19], 1u);
        atomicAdd(&h[__float_as_uint(x.y) >> 19], 1u);
        atomicAdd(&h[__float_as_uint(x.z) >> 19], 1u);
        atomicAdd(&h[__float_as_uint(x.w) >> 19], 1u);
    }
    __syncthreads();
    unsigned* gh = hist + b * NBIN13;
    for (int i = tid; i < NBIN13; i += 1024)
        if (h[i]) atomicAdd(&gh[i], h[i]);
}

// Per image: sum num_pos from k_loss partials; parallel 13-bit select.
__global__ __launch_bounds__(256) void k_sel13(
        const unsigned* __restrict__ hist, const int* __restrict__ pn,
        int* __restrict__ sel, int* __restrict__ remk, int* __restrict__ npos) {
    const int b = blockIdx.x;
    const int tid = threadIdx.x;
    __shared__ int s_np;
    __shared__ int rnp[4];
    int loc = 0;
    for (int i = tid; i < LOSS_X; i += 256) loc += pn[b * LOSS_X + i];
#pragma unroll
    for (int off = 32; off > 0; off >>= 1) loc += __shfl_xor(loc, off);
    int lane = tid & 63, wave = tid >> 6;
    if (lane == 0) rnp[wave] = loc;
    __syncthreads();
    if (tid == 0) { int s = rnp[0] + rnp[1] + rnp[2] + rnp[3]; s_np = s; npos[b] = s; }
    __syncthreads();
    long long k = (long long)NEG_POS * s_np;
    if (k > P_ - 1) k = P_ - 1;
    if (k <= 0) { if (tid == 0) sel[b] = -1; return; }

    __shared__ int s_bin;
    __shared__ unsigned s_rem;
    topk_select<NBIN13>(hist + b * NBIN13, (unsigned)k, &s_bin, &s_rem);
    __syncthreads();
    if (tid == 0) { sel[b] = s_bin; remk[b] = (int)s_rem; }
}

// Scan 2: 8-bit histogram (bits 18..11) of in-bin elements.
__global__ __launch_bounds__(1024) void k_hist8(
        const float* __restrict__ ce_neg, const int* __restrict__ sel,
        unsigned* __restrict__ hist8) {
    const int b = blockIdx.y;
    const int s13 = sel[b];
    if (s13 < 0) return;
    const int tid = threadIdx.x;
    __shared__ unsigned h[NBIN8];
    if (tid < NBIN8) h[tid] = 0;
    __syncthreads();
    const float4* v4 = (const float4*)(ce_neg + (size_t)b * P_);
    const int c4 = P_ / SCAN_BLKS / 4;
    const int s4 = blockIdx.x * c4;
    for (int i = s4 + tid; i < s4 + c4; i += 1024) {
        float4 x = v4[i];
        unsigned u0 = __float_as_uint(x.x), u1 = __float_as_uint(x.y);
        unsigned u2 = __float_as_uint(x.z), u3 = __float_as_uint(x.w);
        if ((int)(u0 >> 19) == s13) atomicAdd(&h[(u0 >> 11) & 255u], 1u);
        if ((int)(u1 >> 19) == s13) atomicAdd(&h[(u1 >> 11) & 255u], 1u);
        if ((int)(u2 >> 19) == s13) atomicAdd(&h[(u2 >> 11) & 255u], 1u);
        if ((int)(u3 >> 19) == s13) atomicAdd(&h[(u3 >> 11) & 255u], 1u);
    }
    __syncthreads();
    if (tid < NBIN8 && h[tid]) atomicAdd(&hist8[b * NBIN8 + tid], h[tid]);
}

// Per image: parallel 8-bit select; extend prefix.
__global__ __launch_bounds__(256) void k_sel8(
        const unsigned* __restrict__ hist8, const int* __restrict__ sel,
        unsigned* __restrict__ pref, int* __restrict__ remk) {
    const int b = blockIdx.x;
    if (sel[b] < 0) return;
    __shared__ int s_bin;
    __shared__ unsigned s_rem;
    topk_select<NBIN8>(hist8 + b * NBIN8, (unsigned)remk[b], &s_bin, &s_rem);
    __syncthreads();
    if (threadIdx.x == 0) {
        pref[b] = ((unsigned)sel[b] << 8) | (unsigned)s_bin;   // 21-bit prefix
        remk[b] = (int)s_rem;
    }
}

// Scan 3 (now also the LAST full scan): 11-bit histogram of in-prefix
// elements AND f64 sum of all elements strictly above the prefix bucket
// (block reduce + one atomic). Replaces the old hist11 + sumtop pair:
// an 11-bit bin under a fixed 21-bit prefix determines ALL 32 value bits,
// so the above-threshold within-prefix sum is recoverable from counts alone.
__global__ __launch_bounds__(1024) void k_hist11(
        const float* __restrict__ ce_neg, const int* __restrict__ sel,
        const unsigned* __restrict__ pref, unsigned* __restrict__ hist11,
        double* __restrict__ tot) {
    const int b = blockIdx.y;
    if (sel[b] < 0) return;
    const unsigned pf = pref[b];
    const int tid = threadIdx.x;
    __shared__ unsigned h[NBIN11];
    for (int i = tid; i < NBIN11; i += 1024) h[i] = 0;
    __syncthreads();
    const float4* v4 = (const float4*)(ce_neg + (size_t)b * P_);
    const int c4 = P_ / SCAN_BLKS / 4;
    const int s4 = blockIdx.x * c4;
    double above = 0;
    for (int i = s4 + tid; i < s4 + c4; i += 1024) {
        float4 x = v4[i];
        unsigned u0 = __float_as_uint(x.x), u1 = __float_as_uint(x.y);
        unsigned u2 = __float_as_uint(x.z), u3 = __float_as_uint(x.w);
        unsigned h0 = u0 >> 11, h1 = u1 >> 11, h2 = u2 >> 11, h3 = u3 >> 11;
        if (h0 == pf) atomicAdd(&h[u0 & 2047u], 1u); else if (h0 > pf) above += x.x;
        if (h1 == pf) atomicAdd(&h[u1 & 2047u], 1u); else if (h1 > pf) above += x.y;
        if (h2 == pf) atomicAdd(&h[u2 & 2047u], 1u); else if (h2 > pf) above += x.z;
        if (h3 == pf) atomicAdd(&h[u3 & 2047u], 1u); else if (h3 > pf) above += x.w;
    }
    __syncthreads();
    unsigned* gh = hist11 + b * NBIN11;
    for (int i = tid; i < NBIN11; i += 1024)
        if (h[i]) atomicAdd(&gh[i], h[i]);
    // block reduce the above-prefix sum -> one f64 atomic (sumtop pattern)
#pragma unroll
    for (int off = 32; off > 0; off >>= 1) above += __shfl_xor(above, off);
    __shared__ double rs[16];
    int lane = tid & 63, wave = tid >> 6;
    if (lane == 0) rs[wave] = above;
    __syncthreads();
    if (tid == 0) {
        double s = 0;
        for (int w = 0; w < 16; ++w) s += rs[w];
        atomicAdd(&tot[2], s);
    }
}

// Per image: parallel 11-bit select -> exact threshold T; add the in-prefix
// above-T sum (Sum cnt[bin]*value(bin), exact: bin fixes all 32 bits) and
// the tie term rem*T to tot[2]. No further data scan needed.
__global__ __launch_bounds__(256) void k_sel11(
        const unsigned* __restrict__ hist11, const int* __restrict__ sel,
        const unsigned* __restrict__ pref, const int* __restrict__ remk,
        double* __restrict__ tot) {
    const int b = blockIdx.x;
    if (sel[b] < 0) return;
    const int tid = threadIdx.x;
    __shared__ int s_bin;
    __shared__ unsigned s_rem;
    topk_select<NBIN11>(hist11 + b * NBIN11, (unsigned)remk[b], &s_bin, &s_rem);
    __syncthreads();
    const unsigned pf = pref[b];
    const unsigned* gh = hist11 + b * NBIN11;
    double a = 0;
    for (int i = s_bin + 1 + tid; i < NBIN11; i += 256) {
        unsigned c = gh[i];
        if (c) a += (double)c * (double)__uint_as_float((pf << 11) | (unsigned)i);
    }
#pragma unroll
    for (int off = 32; off > 0; off >>= 1) a += __shfl_xor(a, off);
    __shared__ double rs[4];
    int lane = tid & 63, wave = tid >> 6;
    if (lane == 0) rs[wave] = a;
    __syncthreads();
    if (tid == 0) {
        unsigned T = (pf << 11) | (unsigned)s_bin;
        double s = rs[0] + rs[1] + rs[2] + rs[3];
        s += (double)s_rem * (double)__uint_as_float(T);   // ties at T
        atomicAdd(&tot[2], s);
    }
}

// Final: reduce k_loss partials (box/landm/pos-ce), add mined tot[2], divide.
__global__ __launch_bounds__(1024) void k_final(
        const double* __restrict__ pb, const double* __restrict__ pl,
        const double* __restrict__ pc, const int* __restrict__ npos,
        const double* __restrict__ tot, float* __restrict__ out) {
    int tid = threadIdx.x;
    double sb = 0, sl = 0, sc = 0;
    for (int i = tid; i < LOSS_BLOCKS; i += 1024) {
        sb += pb[i]; sl += pl[i]; sc += pc[i];
    }
#pragma unroll
    for (int off = 32; off > 0; off >>= 1) {
        sb += __shfl_xor(sb, off);
        sl += __shfl_xor(sl, off);
        sc += __shfl_xor(sc, off);
    }
    __shared__ double rb[16], rl[16], rc[16];
    int lane = tid & 63, wave = tid >> 6;
    if (lane == 0) { rb[wave] = sb; rl[wave] = sl; rc[wave] = sc; }
    __syncthreads();
    if (tid == 0) {
        double b2 = 0, l2 = 0, c2 = 0;
        for (int w = 0; w < 16; ++w) { b2 += rb[w]; l2 += rl[w]; c2 += rc[w]; }
        long long tp = 0;
        for (int b = 0; b < B_; ++b) tp += npos[b];
        double n = tp > 0 ? (double)tp : 1.0;
        out[0] = (float)(b2 / n);             // loss_box
        out[1] = (float)((c2 + tot[2]) / n);  // loss_c (pos part + mined negs)
        out[2] = (float)(l2 / n);             // loss_landm
    }
}

// ---------------- launch ----------------
extern "C" void kernel_launch(void* const* d_in, const int* in_sizes, int n_in,
                              void* d_out, int out_size, void* d_ws, size_t ws_size,
                              hipStream_t stream) {
    const float* conf    = (const float*)d_in[0];
    const float* loc     = (const float*)d_in[1];
    const float* landm   = (const float*)d_in[2];
    const float* priors  = (const float*)d_in[3];
    const float* targets = (const float*)d_in[4];

    char* ws = (char*)d_ws;
    double* tot = (double*)ws;                                   // 4 doubles @0
    int* npos = (int*)(ws + 64);
    int* sel  = (int*)(ws + 128);
    int* remk = (int*)(ws + 192);
    unsigned* pref = (unsigned*)(ws + 256);
    unsigned long long* pack = (unsigned long long*)(ws + 512);  // 512 u64
    unsigned* hist13 = (unsigned*)(ws + 4608);                   // 512 KB
    unsigned* hist8  = hist13 + (size_t)B_ * NBIN13;             // 16 KB
    unsigned* hist11 = hist8 + (size_t)B_ * NBIN8;               // 128 KB
    size_t zero_bytes = 4608 + (size_t)B_ * (NBIN13 + NBIN8 + NBIN11) * 4;
    size_t big = (zero_bytes + 255) & ~(size_t)255;
    size_t BP = (size_t)B_ * P_;
    unsigned char* bt = (unsigned char*)(ws + big);              // 2 MB (u8)
    float* ce_neg = (float*)(ws + big + BP);                     // 8.4 MB
    char* part = ws + big + BP * 5;
    double* pb = (double*)part;
    double* pl = (double*)(part + LOSS_BLOCKS * 8);
    double* pc = (double*)(part + LOSS_BLOCKS * 16);
    int*    pn = (int*)(part + LOSS_BLOCKS * 24);

    // one memset zeroes: tot, npos, sel/remk/pref, pack, all histograms
    hipMemsetAsync(ws, 0, zero_bytes, stream);
    k_match<<<dim3(P_ / (256 * UNR), B_), 256, 0, stream>>>(
        (const float4*)priors, targets, bt, pack);
    k_override<<<1, 64, 0, stream>>>(pack, bt);
    k_loss<<<dim3(LOSS_X, B_), 256, 0, stream>>>(
        (const float2*)conf, (const float4*)loc, landm, (const float4*)priors,
        targets, bt, ce_neg, pb, pl, pc, pn);
    k_hist13<<<dim3(SCAN_BLKS, B_), 1024, 0, stream>>>(ce_neg, hist13);
    k_sel13<<<B_, 256, 0, stream>>>(hist13, pn, sel, remk, npos);
    k_hist8<<<dim3(SCAN_BLKS, B_), 1024, 0, stream>>>(ce_neg, sel, hist8);
    k_sel8<<<B_, 256, 0, stream>>>(hist8, sel, pref, remk);
    k_hist11<<<dim3(SCAN_BLKS, B_), 1024, 0, stream>>>(ce_neg, sel, pref, hist11, tot);
    k_sel11<<<B_, 256, 0, stream>>>(hist11, sel, pref, remk, tot);
    k_final<<<1, 1024, 0, stream>>>(pb, pl, pc, npos, tot, (float*)d_out);
}

// Round 15
// 126.672 us; speedup vs baseline: 3.0187x; 1.0010x over previous
//
#include <hip/hip_runtime.h>
#include <math.h>

// Problem constants (from reference)
#define B_ 16
#define P_ 131072
#define G_ 32
constexpr float OVER_THR = 0.35f;
constexpr float VAR0 = 0.1f;
constexpr float VAR1 = 0.2f;
constexpr int NEG_POS = 7;
constexpr int UNR = 8;                         // priors per thread in k_match
constexpr int LOSS_X = P_ / 256;               // 512 blocks per image in k_loss
constexpr int LOSS_BLOCKS = LOSS_X * B_;       // 8192 partials
constexpr int NBIN13 = 8192;                   // level 1: float bits 31..19
constexpr int NBIN8 = 256;                     // level 2: bits 18..11
constexpr int NBIN11 = 2048;                   // level 3: bits 10..0
constexpr int SCAN_BLKS = 16;                  // blocks per image in scans

// ---------------- helpers ----------------
__device__ inline float s1(float d) {            // smooth L1
    d = fabsf(d);
    return d < 1.f ? 0.5f * d * d : d - 0.5f;
}

__device__ inline unsigned long long shfl_xor_u64(unsigned long long x, int m) {
    unsigned lo = (unsigned)x, hi = (unsigned)(x >> 32);
    lo = __shfl_xor(lo, m);
    hi = __shfl_xor(hi, m);
    return ((unsigned long long)hi << 32) | lo;
}

// Block-parallel top-k bin selection (256 threads).
template <int NB>
__device__ void topk_select(const unsigned* __restrict__ h, unsigned rem,
                            int* out_bin, unsigned* out_rem) {
    constexpr int CHUNK = NB / 256;
    const int tid = threadIdx.x;
    unsigned cnt[CHUNK];
    unsigned csum = 0;
#pragma unroll
    for (int j = 0; j < CHUNK; ++j) { cnt[j] = h[tid * CHUNK + j]; csum += cnt[j]; }
    __shared__ unsigned ss[256];
    ss[tid] = csum;
    __syncthreads();
    // Hillis-Steele suffix scan: ss[t] = sum over threads >= t (higher bins)
    for (int off = 1; off < 256; off <<= 1) {
        unsigned other = (tid + off < 256) ? ss[tid + off] : 0u;
        __syncthreads();
        ss[tid] += other;
        __syncthreads();
    }
    unsigned incl = ss[tid];
    unsigned excl = incl - csum;               // strictly above this chunk
    if (excl < rem && incl >= rem) {           // crossing chunk (unique)
        unsigned r = rem - excl, cum = 0;
        int selbin = tid * CHUNK;
#pragma unroll
        for (int j = CHUNK - 1; j >= 0; --j) {
            unsigned c = cnt[j];
            if (cum + c >= r) { selbin = tid * CHUNK + j; r = r - cum; break; }
            cum += c;
        }
        *out_bin = selbin;
        *out_rem = r;
    }
}

// ---------------- kernels ----------------
// k_match: round-14 body; launch_bounds (256,3)->(256,4) so all 1024 blocks
// are co-resident (4 blocks/CU x 256 CU) -- removes the 768+256 two-round
// tail where the second round ran at 25% machine utilization.
__global__ __launch_bounds__(256, 4) void k_match(
        const float4* __restrict__ priors4, const float* __restrict__ targets,
        unsigned char* __restrict__ bt, unsigned long long* __restrict__ pack) {
    const int b = blockIdx.y;
    const int base = blockIdx.x * (256 * UNR);
    const int tid = threadIdx.x;
    __shared__ unsigned long long red[G_][4];

    float px1[UNR], py1[UNR], px2[UNR], py2[UNR], pap[UNR], best[UNR];
    int bidx[UNR];
#pragma unroll
    for (int j = 0; j < UNR; ++j) {
        float4 pr = priors4[base + j * 256 + tid];
        px1[j] = pr.x - pr.z * 0.5f;  py1[j] = pr.y - pr.w * 0.5f;
        px2[j] = pr.x + pr.z * 0.5f;  py2[j] = pr.y + pr.w * 0.5f;
        pap[j] = pr.z * pr.w;
        best[j] = -1.0f; bidx[j] = 0;
    }
    const int lane = tid & 63, wave = tid >> 6;
    const float* tgb = targets + (size_t)b * G_ * 15;
#pragma unroll 1
    for (int g = 0; g < G_; ++g) {
        const float* tp = tgb + g * 15;        // block-uniform -> s_load
        float t0 = tp[0], t1 = tp[1], t2 = tp[2], t3 = tp[3];
        float ta = (t2 - t0) * (t3 - t1);
        float gb = -1.0f; int gj = 0;
#pragma unroll
        for (int j = 0; j < UNR; ++j) {
            float iw = fminf(t2, px2[j]) - fmaxf(t0, px1[j]);
            float ih = fminf(t3, py2[j]) - fmaxf(t1, py1[j]);
            float inter = fmaxf(iw, 0.f) * fmaxf(ih, 0.f);
            float iou = inter * __builtin_amdgcn_rcpf(ta + pap[j] - inter);
            if (iou > best[j]) { best[j] = iou; bidx[j] = g; }  // first-wins ties
            if (iou > gb) { gb = iou; gj = j; }   // first-j wins = lowest p
        }
        unsigned p = (unsigned)(base + (gj << 8) + tid);
        unsigned long long pk =
            ((unsigned long long)__float_as_uint(gb) << 32) | (unsigned)(~p);
#pragma unroll
        for (int off = 32; off > 0; off >>= 1) {
            unsigned long long o = shfl_xor_u64(pk, off);
            if (o > pk) pk = o;
        }
        if (lane == 0) red[g][wave] = pk;
    }
    __syncthreads();
    if (tid < G_) {
        unsigned long long m = red[tid][0];
#pragma unroll
        for (int w = 1; w < 4; ++w) if (red[tid][w] > m) m = red[tid][w];
        atomicMax(&pack[b * G_ + tid], m);
    }
#pragma unroll
    for (int j = 0; j < UNR; ++j) {
        int p = base + j * 256 + tid;
        bt[(size_t)b * P_ + p] =
            (unsigned char)(bidx[j] | (best[j] >= OVER_THR ? 64 : 0));
    }
}

// Sequential per image: scatter with last-g-wins (numpy semantics).
__global__ void k_override(const unsigned long long* __restrict__ pack,
                           unsigned char* __restrict__ bt) {
    int b = threadIdx.x;
    if (b >= B_) return;
    for (int g = 0; g < G_; ++g) {
        unsigned long long pk = pack[b * G_ + g];
        unsigned p = ~(unsigned)(pk & 0xFFFFFFFFull);
        if (p < P_) bt[(size_t)b * P_ + p] = (unsigned char)(g | 64);
    }
}

// Per prior: CE; positives: smooth-L1 on encoded loc/landm. Partials per block.
__global__ __launch_bounds__(256) void k_loss(
        const float2* __restrict__ conf2, const float4* __restrict__ loc4,
        const float* __restrict__ landm, const float4* __restrict__ priors4,
        const float* __restrict__ targets,
        const unsigned char* __restrict__ bt,
        float* __restrict__ ce_neg,
        double* __restrict__ pb, double* __restrict__ pl,
        double* __restrict__ pc, int* __restrict__ pn) {
    const int b = blockIdx.y;
    const int p = blockIdx.x * 256 + threadIdx.x;
    const int tid = threadIdx.x;
    __shared__ float tg[G_ * 15];
    for (int i = tid; i < G_ * 15; i += 256) tg[i] = targets[(size_t)b * G_ * 15 + i];
    __syncthreads();

    const size_t gp = (size_t)b * P_ + p;
    unsigned char bv = bt[gp];
    int ti = bv & 63;
    bool thr_ok = (bv & 64) != 0;               // ov >= OVER_THR (or override)
    const float* t = &tg[ti * 15];
    float label = t[14];
    int conf_t = thr_ok ? (int)label : 0;
    bool pos = conf_t > 0;
    int cls = conf_t > 0 ? conf_t : 0;

    float2 c2 = conf2[gp];
    float mx = fmaxf(c2.x, c2.y);
    float lse = mx + logf(expf(c2.x - mx) + expf(c2.y - mx));
    float ce = lse - (cls ? c2.y : c2.x);
    ce_neg[gp] = (!pos && conf_t >= 0) ? ce : 0.f;

    float lb = 0.f, ll = 0.f;
    if (pos) {
        float4 pr = priors4[p];
        float vx = VAR0 * pr.z, vy = VAR0 * pr.w;
        float g0 = ((t[0] + t[2]) * 0.5f - pr.x) / vx;
        float g1 = ((t[1] + t[3]) * 0.5f - pr.y) / vy;
        float g2 = logf((t[2] - t[0]) / pr.z) / VAR1;
        float g3 = logf((t[3] - t[1]) / pr.w) / VAR1;
        float4 ld = loc4[gp];
        lb = s1(ld.x - g0) + s1(ld.y - g1) + s1(ld.z - g2) + s1(ld.w - g3);
        const float* lmp = landm + gp * 10;
#pragma unroll
        for (int i = 0; i < 5; ++i) {
            float2 lm = *(const float2*)(lmp + 2 * i);
            ll += s1(lm.x - (t[4 + 2 * i] - pr.x) / vx)
                + s1(lm.y - (t[5 + 2 * i] - pr.y) / vy);
        }
    }
    double vb = lb, vl = ll, vc = pos ? (double)ce : 0.0;
    int vp = pos ? 1 : 0;
#pragma unroll
    for (int off = 32; off > 0; off >>= 1) {
        vb += __shfl_xor(vb, off);
        vl += __shfl_xor(vl, off);
        vc += __shfl_xor(vc, off);
        vp += __shfl_xor(vp, off);
    }
    __shared__ double rb[4], rl[4], rc[4];
    __shared__ int rp[4];
    int lane = tid & 63, wave = tid >> 6;
    if (lane == 0) { rb[wave] = vb; rl[wave] = vl; rc[wave] = vc; rp[wave] = vp; }
    __syncthreads();
    if (tid == 0) {
        double sb = 0, sl = 0, sc = 0; int sp = 0;
        for (int w = 0; w < 4; ++w) { sb += rb[w]; sl += rl[w]; sc += rc[w]; sp += rp[w]; }
        int bi = blockIdx.y * LOSS_X + blockIdx.x;
        pb[bi] = sb; pl[bi] = sl; pc[bi] = sc; pn[bi] = sp;
    }
}

// Scan 1: 13-bit count histogram of ce_neg float bits, per image. float4 loads.
__global__ __launch_bounds__(1024) void k_hist13(
        const float* __restrict__ ce_neg, unsigned* __restrict__ hist) {
    const int b = blockIdx.y;
    const int tid = threadIdx.x;
    __shared__ unsigned h[NBIN13];
    for (int i = tid; i < NBIN13; i += 1024) h[i] = 0;
    __syncthreads();
    const float4* v4 = (const float4*)(ce_neg + (size_t)b * P_);
    const int c4 = P_ / SCAN_BLKS / 4;
    const int s4 = blockIdx.x * c4;
    for (int i = s4 + tid; i < s4 + c4; i += 1024) {
        float4 x = v4[i];
        atomicAdd(&h[__float_as_uint(x.x) >> 19], 1u);
        atomicAdd(&h[__float_as_uint(x.y) >> 19], 1u);
        atomicAdd(&h[__float_as_uint(x.z) >> 19], 1u);
        atomicAdd(&h[__float_as_uint(x.w) >> 19], 1u);
    }
    __syncthreads();
    unsigned* gh = hist + b * NBIN13;
    for (int i = tid; i < NBIN13; i += 1024)
        if (h[i]) atomicAdd(&gh[i], h[i]);
}

// Per image: sum num_pos from k_loss partials; parallel 13-bit select.
__global__ __launch_bounds__(256) void k_sel13(
        const unsigned* __restrict__ hist, const int* __restrict__ pn,
        int* __restrict__ sel, int* __restrict__ remk, int* __restrict__ npos) {
    const int b = blockIdx.x;
    const int tid = threadIdx.x;
    __shared__ int s_np;
    __shared__ int rnp[4];
    int loc = 0;
    for (int i = tid; i < LOSS_X; i += 256) loc += pn[b * LOSS_X + i];
#pragma unroll
    for (int off = 32; off > 0; off >>= 1) loc += __shfl_xor(loc, off);
    int lane = tid & 63, wave = tid >> 6;
    if (lane == 0) rnp[wave] = loc;
    __syncthreads();
    if (tid == 0) { int s = rnp[0] + rnp[1] + rnp[2] + rnp[3]; s_np = s; npos[b] = s; }
    __syncthreads();
    long long k = (long long)NEG_POS * s_np;
    if (k > P_ - 1) k = P_ - 1;
    if (k <= 0) { if (tid == 0) sel[b] = -1; return; }

    __shared__ int s_bin;
    __shared__ unsigned s_rem;
    topk_select<NBIN13>(hist + b * NBIN13, (unsigned)k, &s_bin, &s_rem);
    __syncthreads();
    if (tid == 0) { sel[b] = s_bin; remk[b] = (int)s_rem; }
}

// Scan 2: 8-bit histogram (bits 18..11) of in-bin elements.
__global__ __launch_bounds__(1024) void k_hist8(
        const float* __restrict__ ce_neg, const int* __restrict__ sel,
        unsigned* __restrict__ hist8) {
    const int b = blockIdx.y;
    const int s13 = sel[b];
    if (s13 < 0) return;
    const int tid = threadIdx.x;
    __shared__ unsigned h[NBIN8];
    if (tid < NBIN8) h[tid] = 0;
    __syncthreads();
    const float4* v4 = (const float4*)(ce_neg + (size_t)b * P_);
    const int c4 = P_ / SCAN_BLKS / 4;
    const int s4 = blockIdx.x * c4;
    for (int i = s4 + tid; i < s4 + c4; i += 1024) {
        float4 x = v4[i];
        unsigned u0 = __float_as_uint(x.x), u1 = __float_as_uint(x.y);
        unsigned u2 = __float_as_uint(x.z), u3 = __float_as_uint(x.w);
        if ((int)(u0 >> 19) == s13) atomicAdd(&h[(u0 >> 11) & 255u], 1u);
        if ((int)(u1 >> 19) == s13) atomicAdd(&h[(u1 >> 11) & 255u], 1u);
        if ((int)(u2 >> 19) == s13) atomicAdd(&h[(u2 >> 11) & 255u], 1u);
        if ((int)(u3 >> 19) == s13) atomicAdd(&h[(u3 >> 11) & 255u], 1u);
    }
    __syncthreads();
    if (tid < NBIN8 && h[tid]) atomicAdd(&hist8[b * NBIN8 + tid], h[tid]);
}

// Per image: parallel 8-bit select; extend prefix.
__global__ __launch_bounds__(256) void k_sel8(
        const unsigned* __restrict__ hist8, const int* __restrict__ sel,
        unsigned* __restrict__ pref, int* __restrict__ remk) {
    const int b = blockIdx.x;
    if (sel[b] < 0) return;
    __shared__ int s_bin;
    __shared__ unsigned s_rem;
    topk_select<NBIN8>(hist8 + b * NBIN8, (unsigned)remk[b], &s_bin, &s_rem);
    __syncthreads();
    if (threadIdx.x == 0) {
        pref[b] = ((unsigned)sel[b] << 8) | (unsigned)s_bin;   // 21-bit prefix
        remk[b] = (int)s_rem;
    }
}

// Scan 3 (the LAST full scan): 11-bit histogram of in-prefix elements AND f64
// sum of all elements strictly above the prefix bucket (block reduce + one
// atomic). An 11-bit bin under a fixed 21-bit prefix determines ALL 32 value
// bits, so the rest of the mined sum is recoverable from counts alone.
__global__ __launch_bounds__(1024) void k_hist11(
        const float* __restrict__ ce_neg, const int* __restrict__ sel,
        const unsigned* __restrict__ pref, unsigned* __restrict__ hist11,
        double* __restrict__ tot) {
    const int b = blockIdx.y;
    if (sel[b] < 0) return;
    const unsigned pf = pref[b];
    const int tid = threadIdx.x;
    __shared__ unsigned h[NBIN11];
    for (int i = tid; i < NBIN11; i += 1024) h[i] = 0;
    __syncthreads();
    const float4* v4 = (const float4*)(ce_neg + (size_t)b * P_);
    const int c4 = P_ / SCAN_BLKS / 4;
    const int s4 = blockIdx.x * c4;
    double above = 0;
    for (int i = s4 + tid; i < s4 + c4; i += 1024) {
        float4 x = v4[i];
        unsigned u0 = __float_as_uint(x.x), u1 = __float_as_uint(x.y);
        unsigned u2 = __float_as_uint(x.z), u3 = __float_as_uint(x.w);
        unsigned h0 = u0 >> 11, h1 = u1 >> 11, h2 = u2 >> 11, h3 = u3 >> 11;
        if (h0 == pf) atomicAdd(&h[u0 & 2047u], 1u); else if (h0 > pf) above += x.x;
        if (h1 == pf) atomicAdd(&h[u1 & 2047u], 1u); else if (h1 > pf) above += x.y;
        if (h2 == pf) atomicAdd(&h[u2 & 2047u], 1u); else if (h2 > pf) above += x.z;
        if (h3 == pf) atomicAdd(&h[u3 & 2047u], 1u); else if (h3 > pf) above += x.w;
    }
    __syncthreads();
    unsigned* gh = hist11 + b * NBIN11;
    for (int i = tid; i < NBIN11; i += 1024)
        if (h[i]) atomicAdd(&gh[i], h[i]);
    // block reduce the above-prefix sum -> one f64 atomic (sumtop pattern)
#pragma unroll
    for (int off = 32; off > 0; off >>= 1) above += __shfl_xor(above, off);
    __shared__ double rs[16];
    int lane = tid & 63, wave = tid >> 6;
    if (lane == 0) rs[wave] = above;
    __syncthreads();
    if (tid == 0) {
        double s = 0;
        for (int w = 0; w < 16; ++w) s += rs[w];
        atomicAdd(&tot[2], s);
    }
}

// Per image: parallel 11-bit select -> exact threshold T; add the in-prefix
// above-T sum (Sum cnt[bin]*value(bin), exact) and the tie term rem*T.
__global__ __launch_bounds__(256) void k_sel11(
        const unsigned* __restrict__ hist11, const int* __restrict__ sel,
        const unsigned* __restrict__ pref, const int* __restrict__ remk,
        double* __restrict__ tot) {
    const int b = blockIdx.x;
    if (sel[b] < 0) return;
    const int tid = threadIdx.x;
    __shared__ int s_bin;
    __shared__ unsigned s_rem;
    topk_select<NBIN11>(hist11 + b * NBIN11, (unsigned)remk[b], &s_bin, &s_rem);
    __syncthreads();
    const unsigned pf = pref[b];
    const unsigned* gh = hist11 + b * NBIN11;
    double a = 0;
    for (int i = s_bin + 1 + tid; i < NBIN11; i += 256) {
        unsigned c = gh[i];
        if (c) a += (double)c * (double)__uint_as_float((pf << 11) | (unsigned)i);
    }
#pragma unroll
    for (int off = 32; off > 0; off >>= 1) a += __shfl_xor(a, off);
    __shared__ double rs[4];
    int lane = tid & 63, wave = tid >> 6;
    if (lane == 0) rs[wave] = a;
    __syncthreads();
    if (tid == 0) {
        unsigned T = (pf << 11) | (unsigned)s_bin;
        double s = rs[0] + rs[1] + rs[2] + rs[3];
        s += (double)s_rem * (double)__uint_as_float(T);   // ties at T
        atomicAdd(&tot[2], s);
    }
}

// Final: reduce k_loss partials (box/landm/pos-ce), add mined tot[2], divide.
__global__ __launch_bounds__(1024) void k_final(
        const double* __restrict__ pb, const double* __restrict__ pl,
        const double* __restrict__ pc, const int* __restrict__ npos,
        const double* __restrict__ tot, float* __restrict__ out) {
    int tid = threadIdx.x;
    double sb = 0, sl = 0, sc = 0;
    for (int i = tid; i < LOSS_BLOCKS; i += 1024) {
        sb += pb[i]; sl += pl[i]; sc += pc[i];
    }
#pragma unroll
    for (int off = 32; off > 0; off >>= 1) {
        sb += __shfl_xor(sb, off);
        sl += __shfl_xor(sl, off);
        sc += __shfl_xor(sc, off);
    }
    __shared__ double rb[16], rl[16], rc[16];
    int lane = tid & 63, wave = tid >> 6;
    if (lane == 0) { rb[wave] = sb; rl[wave] = sl; rc[wave] = sc; }
    __syncthreads();
    if (tid == 0) {
        double b2 = 0, l2 = 0, c2 = 0;
        for (int w = 0; w < 16; ++w) { b2 += rb[w]; l2 += rl[w]; c2 += rc[w]; }
        long long tp = 0;
        for (int b = 0; b < B_; ++b) tp += npos[b];
        double n = tp > 0 ? (double)tp : 1.0;
        out[0] = (float)(b2 / n);             // loss_box
        out[1] = (float)((c2 + tot[2]) / n);  // loss_c (pos part + mined negs)
        out[2] = (float)(l2 / n);             // loss_landm
    }
}

// ---------------- launch ----------------
extern "C" void kernel_launch(void* const* d_in, const int* in_sizes, int n_in,
                              void* d_out, int out_size, void* d_ws, size_t ws_size,
                              hipStream_t stream) {
    const float* conf    = (const float*)d_in[0];
    const float* loc     = (const float*)d_in[1];
    const float* landm   = (const float*)d_in[2];
    const float* priors  = (const float*)d_in[3];
    const float* targets = (const float*)d_in[4];

    char* ws = (char*)d_ws;
    double* tot = (double*)ws;                                   // 4 doubles @0
    int* npos = (int*)(ws + 64);
    int* sel  = (int*)(ws + 128);
    int* remk = (int*)(ws + 192);
    unsigned* pref = (unsigned*)(ws + 256);
    unsigned long long* pack = (unsigned long long*)(ws + 512);  // 512 u64
    unsigned* hist13 = (unsigned*)(ws + 4608);                   // 512 KB
    unsigned* hist8  = hist13 + (size_t)B_ * NBIN13;             // 16 KB
    unsigned* hist11 = hist8 + (size_t)B_ * NBIN8;               // 128 KB
    size_t zero_bytes = 4608 + (size_t)B_ * (NBIN13 + NBIN8 + NBIN11) * 4;
    size_t big = (zero_bytes + 255) & ~(size_t)255;
    size_t BP = (size_t)B_ * P_;
    unsigned char* bt = (unsigned char*)(ws + big);              // 2 MB (u8)
    float* ce_neg = (float*)(ws + big + BP);                     // 8.4 MB
    char* part = ws + big + BP * 5;
    double* pb = (double*)part;
    double* pl = (double*)(part + LOSS_BLOCKS * 8);
    double* pc = (double*)(part + LOSS_BLOCKS * 16);
    int*    pn = (int*)(part + LOSS_BLOCKS * 24);

    // one memset zeroes: tot, npos, sel/remk/pref, pack, all histograms
    hipMemsetAsync(ws, 0, zero_bytes, stream);
    k_match<<<dim3(P_ / (256 * UNR), B_), 256, 0, stream>>>(
        (const float4*)priors, targets, bt, pack);
    k_override<<<1, 64, 0, stream>>>(pack, bt);
    k_loss<<<dim3(LOSS_X, B_), 256, 0, stream>>>(
        (const float2*)conf, (const float4*)loc, landm, (const float4*)priors,
        targets, bt, ce_neg, pb, pl, pc, pn);
    k_hist13<<<dim3(SCAN_BLKS, B_), 1024, 0, stream>>>(ce_neg, hist13);
    k_sel13<<<B_, 256, 0, stream>>>(hist13, pn, sel, remk, npos);
    k_hist8<<<dim3(SCAN_BLKS, B_), 1024, 0, stream>>>(ce_neg, sel, hist8);
    k_sel8<<<B_, 256, 0, stream>>>(hist8, sel, pref, remk);
    k_hist11<<<dim3(SCAN_BLKS, B_), 1024, 0, stream>>>(ce_neg, sel, pref, hist11, tot);
    k_sel11<<<B_, 256, 0, stream>>>(hist11, sel, pref, remk, tot);
    k_final<<<1, 1024, 0, stream>>>(pb, pl, pc, npos, tot, (float*)d_out);
}